// Round 13
// baseline (6583.344 us; speedup 1.0000x reference)
//
#include <hip/hip_runtime.h>

typedef __attribute__((ext_vector_type(8))) short short8;       // bf16x8 MFMA frag
typedef __attribute__((ext_vector_type(8))) unsigned short ushort8;
typedef __attribute__((ext_vector_type(4))) float f32x4;
typedef __attribute__((ext_vector_type(4))) int i32x4;

#define T_STEPS 2048

static __device__ __forceinline__ unsigned short f2bf(float f) {
  unsigned u = __builtin_bit_cast(unsigned, f);
  unsigned r = u + 0x7fffu + ((u >> 16) & 1u);   // RNE
  return (unsigned short)(r >> 16);
}
static __device__ __forceinline__ float bf2f(unsigned short h) {
  unsigned u = ((unsigned)h) << 16;
  return __builtin_bit_cast(float, u);
}
static __device__ __forceinline__ float fast_sigmoid(float v) {
  return __builtin_amdgcn_rcpf(1.0f + __expf(-v));
}
static __device__ __forceinline__ float fast_tanh(float v) {
  return 1.0f - 2.0f * __builtin_amdgcn_rcpf(1.0f + __expf(2.0f * v));
}

// W pack (proven): p[s][g][kt][l][e], element = W[k][c],
// k = kt*32 + (l>>4)*8 + e ; c = g*512 + s*16 + (l&15).
//
// h exchange: per-GROUP ring of 8 slots x 4 REPLICAS.
// hbuf[group][slot][rep][plane][4*512] bf16; slot=t&7; tag=(t>>3)&3 in the
// 2 LSBs of every ushort. Producer writes ALL 4 replicas (fire-and-forget
// write-through -> shared XCD L2 for homogeneous groups). Consumer attempt r
// reads replica r: an address untouched this step cannot be L1-stale -> each
// retry is a FRESH L2 look (~300cy), covering ~1us+ of producer skew for
// ~1/5 the cost of the flag+MALL path. Tag-alias safety: same slot+replica
// with same tag recurs only after 32 steps -- an L1 line cannot survive that.
// Deep fallback (flag spin + agent-atomic MALL loop) is r10-proven live.
__global__ void prep_kernel(const float* __restrict__ Wx, const float* __restrict__ Wh,
                            const float* __restrict__ h0,
                            unsigned short* __restrict__ wxp, unsigned short* __restrict__ whp,
                            unsigned short* __restrict__ hbuf, int* __restrict__ ctl,
                            int* __restrict__ flags) {
  int idx = blockIdx.x * 256 + threadIdx.x;
  if (idx < 2097152) {
    int which = idx >> 20;
    int r = idx & 1048575;
    int e = r & 7;
    int l = (r >> 3) & 63;
    int kt = (r >> 9) & 15;
    int g = (r >> 13) & 3;
    int s = r >> 15;
    int k = kt * 32 + ((l >> 4) << 3) + e;
    int c = g * 512 + s * 16 + (l & 15);
    const float* W = which ? Wh : Wx;
    unsigned short* dst = which ? whp : wxp;
    dst[r] = f2bf(W[k * 2048 + c]);
  } else if (idx < 2097152 + 16384) {
    int i = idx - 2097152;                 // b*512 + k
    int bg = i >> 9;
    int k = i & 511;
    int g = bg >> 2, bl = bg & 3;
    float v = h0[i];
    unsigned short hi = f2bf(v) & 0xFFFCu;                 // tag(step 0)=0
    unsigned short lo = f2bf(v - bf2f(hi)) & 0xFFFCu;
    unsigned short* d = hbuf + g * 131072;                 // group base, slot 0
#pragma unroll
    for (int rep = 0; rep < 4; ++rep) {
      d[rep * 4096 + bl * 512 + k] = hi;
      d[rep * 4096 + 2048 + bl * 512 + k] = lo;
    }
  } else if (idx < 2097152 + 16384 + 9) {
    ctl[idx - (2097152 + 16384)] = 0;      // ctl[0..7]=XCD tickets, ctl[8]=orphan rank
  } else if (idx < 2097152 + 16384 + 9 + 8192) {
    flags[idx - (2097152 + 16384 + 9)] = 0;   // 8 groups x 32 slices x 32-int spacing
  }
}

// Transpose x (b,t,d) f32 -> xt (t,b,d) bf16 (unchanged).
__global__ void xprep_kernel(const float* __restrict__ x, unsigned short* __restrict__ xb) {
  size_t i8 = ((size_t)blockIdx.x * 256 + threadIdx.x) * 8;
  int t = (int)(i8 >> 14);
  int r = (int)(i8 & 16383);
  int b = r >> 9;
  int d = r & 511;
  const float* src = x + ((size_t)b * 2048 + (size_t)t) * 512 + d;
  f32x4 a = *(const f32x4*)src;
  f32x4 c = *(const f32x4*)(src + 4);
  ushort8 o;
#pragma unroll
  for (int e = 0; e < 4; ++e) {
    o[e] = f2bf(a[e]);
    o[e + 4] = f2bf(c[e]);
  }
  *(ushort8*)(xb + i8) = o;
}

__global__ __launch_bounds__(256, 1) void scan_kernel(
    const unsigned short* __restrict__ xb, const float* __restrict__ bias,
    const unsigned short* __restrict__ wxp, const unsigned short* __restrict__ whp,
    unsigned short* __restrict__ hbuf, float* __restrict__ out, int* __restrict__ ctl,
    int* __restrict__ flags) {
  __shared__ unsigned short WxL[4][16][512];   // 64 KB
  __shared__ unsigned short WhL[4][16][512];   // 64 KB
  __shared__ float gLDS[2][4][4][4][16];       // 8 KB [parity][wave][gate][batch][unit]
  __shared__ int s_g, s_s, s_dir;

  const int tid = threadIdx.x;
  const int lane = tid & 63;
  const int gw = tid >> 6;                     // wave id == K-slice id

  if (tid == 0) {
    unsigned xcc;
    asm volatile("s_getreg_b32 %0, hwreg(HW_REG_XCC_ID)" : "=s"(xcc));
    xcc &= 7;
    int tk = __hip_atomic_fetch_add(&ctl[xcc], 1, __ATOMIC_RELAXED,
                                    __HIP_MEMORY_SCOPE_AGENT);
    int c[8];
    for (;;) {                                 // settle: all 256 ticket first
      int tot = 0;
#pragma unroll
      for (int x = 0; x < 8; ++x) {
        c[x] = __hip_atomic_load(&ctl[x], __ATOMIC_RELAXED, __HIP_MEMORY_SCOPE_AGENT);
        tot += c[x];
      }
      if (tot >= 256) break;
      __builtin_amdgcn_s_sleep(2);
    }
    int g = -1, s = -1, dir = 0;
    if (tk < 32) {
      g = (int)xcc;
      s = tk;
      dir = (c[xcc] >= 32);                    // fully local group => L2 fast path
    } else {
      int rank = __hip_atomic_fetch_add(&ctl[8], 1, __ATOMIC_RELAXED,
                                        __HIP_MEMORY_SCOPE_AGENT);
      int acc2 = 0;
      for (int x = 0; x < 8; ++x) {
        int n = 32 - c[x];
        if (n < 0) n = 0;
        if (g < 0 && rank < acc2 + n) { g = x; s = c[x] + (rank - acc2); }
        acc2 += n;
      }
      dir = 0;
    }
    s_g = g; s_s = s; s_dir = dir;
  }
  __syncthreads();
  const int g = s_g, s = s_s, use_direct = s_dir;
  if (s < 0 || g < 0) return;

  {
    const ushort8* sx = (const ushort8*)(wxp + (size_t)s * 32768);
    const ushort8* sh = (const ushort8*)(whp + (size_t)s * 32768);
    ushort8* dx = (ushort8*)&WxL[0][0][0];
    ushort8* dh = (ushort8*)&WhL[0][0][0];
    for (int i = tid; i < 4096; i += 256) {
      dx[i] = sx[i];
      dh[i] = sh[i];
    }
  }
  __syncthreads();
  short8 wxf[4][4], whf[4][4];                 // [kt][nt]
#pragma unroll
  for (int kt = 0; kt < 4; ++kt)
#pragma unroll
    for (int nt = 0; nt < 4; ++nt) {
      const int ktg = (gw << 2) + kt;
      wxf[kt][nt] = *(const short8*)&WxL[nt][ktg][lane * 8];
      whf[kt][nt] = *(const short8*)&WhL[nt][ktg][lane * 8];
    }

  const int brow = lane & 3;
  const int kgrp = (lane >> 4) * 8;
  const int gb = lane >> 4;                    // gate-phase batch 0..3
  const int gu = lane & 15;                    // gate-phase unit 0..15
  float bias4[4];
#pragma unroll
  for (int gg2 = 0; gg2 < 4; ++gg2)
    bias4[gg2] = bias[gg2 * 512 + s * 16 + gu];
  float c = 0.f;

  unsigned short* hb = hbuf + g * 131072;      // group ring: 8 slots x 4 reps x 4096
  int* gflags = flags + g * 1024;
  int* wflag = gflags + ((gw << 3) + (lane & 7)) * 32;   // my wave's 8 producers
  int* myflag = gflags + s * 32;
  float* outbase = out + (size_t)(g * 4 + gb) * (2048 * 512) + s * 16 + gu;
  const int xrow = (g * 4 + brow) * 512;
  const int shfl_src = ((lane >> 3) << 4) + ((lane & 7) << 1);

  short8 xf[4];
#pragma unroll
  for (int kt = 0; kt < 4; ++kt) {
    const int k0 = (gw << 7) + (kt << 5) + kgrp;
    xf[kt] = *(const short8*)&xb[xrow + k0];
  }

  for (int t = 0; t < T_STEPS; ++t) {
    const unsigned tag = (unsigned)((t >> 3) & 3);
    const unsigned tp32 = 0x00010001u * tag;
    const unsigned short* srd = hb + (t & 7) * 16384;  // slot base (4 replicas)
    i32x4 q[8];
    bool ok = false;

    // ---- phase B0: issue replica-0 speculative loads (hide under x-MFMAs)
    if (use_direct) {
#pragma unroll
      for (int kt = 0; kt < 4; ++kt) {
        const int k0 = (gw << 7) + (kt << 5) + kgrp;
        q[kt * 2 + 0] = *(const i32x4*)(srd + brow * 512 + k0);
        q[kt * 2 + 1] = *(const i32x4*)(srd + 2048 + brow * 512 + k0);
      }
    }

    // ---- phase A: x-part MFMAs (h-independent; overlap replica-0 latency)
    f32x4 acc[4], accl[4];
#pragma unroll
    for (int nt = 0; nt < 4; ++nt) {
      acc[nt] = (f32x4){0.f, 0.f, 0.f, 0.f};
      accl[nt] = (f32x4){0.f, 0.f, 0.f, 0.f};
    }
#pragma unroll
    for (int kt = 0; kt < 4; ++kt)
#pragma unroll
      for (int nt = 0; nt < 4; ++nt)
        acc[nt] = __builtin_amdgcn_mfma_f32_16x16x32_bf16(xf[kt], wxf[kt][nt], acc[nt], 0, 0, 0);

    // ---- phase B1: check replica 0; retry replicas 1..3 (fresh L2 looks)
    if (use_direct) {
      unsigned bad = 0;
#pragma unroll
      for (int i = 0; i < 8; ++i)
#pragma unroll
        for (int j = 0; j < 4; ++j)
          bad |= (((unsigned)q[i][j]) & 0x00030003u) ^ tp32;
      ok = __all(bad == 0);
      for (int rep = 1; rep < 4 && !ok; ++rep) {
        __builtin_amdgcn_s_sleep(2);                       // constant backoff
        const unsigned short* hrd = srd + rep * 4096;
#pragma unroll
        for (int kt = 0; kt < 4; ++kt) {
          const int k0 = (gw << 7) + (kt << 5) + kgrp;
          q[kt * 2 + 0] = *(const i32x4*)(hrd + brow * 512 + k0);
          q[kt * 2 + 1] = *(const i32x4*)(hrd + 2048 + brow * 512 + k0);
        }
        unsigned bad2 = 0;
#pragma unroll
        for (int i = 0; i < 8; ++i)
#pragma unroll
          for (int j = 0; j < 4; ++j)
            bad2 |= (((unsigned)q[i][j]) & 0x00030003u) ^ tp32;
        ok = __all(bad2 == 0);
      }
    }

    if (!ok) {
      // deep fallback (r10-proven): flag spin, then MALL agent data loop
      if (use_direct && t > 0) {
        int done = (lane >= 8);
        for (;;) {
          if (!done) {
            int old, zero = 0;
            asm volatile("global_atomic_add %0, %1, %2, off sc0\n\t"
                         "s_waitcnt vmcnt(0)"
                         : "=v"(old) : "v"(wflag), "v"(zero) : "memory");
            done = (old >= t);
          }
          if (__all(done)) break;
          __builtin_amdgcn_s_sleep(1);
        }
      }
      const unsigned long long tp64 = 0x0001000100010001ull * (unsigned long long)tag;
      const unsigned long long* h64 = (const unsigned long long*)srd;   // replica 0
      for (;;) {
        unsigned long long bad = 0;
#pragma unroll
        for (int kt = 0; kt < 4; ++kt) {
          const int k0 = (gw << 7) + (kt << 5) + kgrp;
          const int bi = (brow * 512 + k0) >> 2;
          const int bj = (2048 + brow * 512 + k0) >> 2;
          union { unsigned long long u[2]; i32x4 v; } a, b;
          a.u[0] = __hip_atomic_load(h64 + bi, __ATOMIC_RELAXED, __HIP_MEMORY_SCOPE_AGENT);
          a.u[1] = __hip_atomic_load(h64 + bi + 1, __ATOMIC_RELAXED, __HIP_MEMORY_SCOPE_AGENT);
          b.u[0] = __hip_atomic_load(h64 + bj, __ATOMIC_RELAXED, __HIP_MEMORY_SCOPE_AGENT);
          b.u[1] = __hip_atomic_load(h64 + bj + 1, __ATOMIC_RELAXED, __HIP_MEMORY_SCOPE_AGENT);
          q[kt * 2 + 0] = a.v;
          q[kt * 2 + 1] = b.v;
          bad |= (a.u[0] & 0x0003000300030003ull) ^ tp64;
          bad |= (a.u[1] & 0x0003000300030003ull) ^ tp64;
          bad |= (b.u[0] & 0x0003000300030003ull) ^ tp64;
          bad |= (b.u[1] & 0x0003000300030003ull) ^ tp64;
        }
        if (__all(bad == 0)) break;
        __builtin_amdgcn_s_sleep(1);
      }
    }

    // ---- phase D: h-part MFMAs (split chains: hh->acc, hl->accl)
#pragma unroll
    for (int kt = 0; kt < 4; ++kt) {
      short8 hh = __builtin_bit_cast(short8, q[kt * 2 + 0]);
      short8 hl = __builtin_bit_cast(short8, q[kt * 2 + 1]);
#pragma unroll
      for (int nt = 0; nt < 4; ++nt) {
        acc[nt] = __builtin_amdgcn_mfma_f32_16x16x32_bf16(hh, whf[kt][nt], acc[nt], 0, 0, 0);
        accl[nt] = __builtin_amdgcn_mfma_f32_16x16x32_bf16(hl, whf[kt][nt], accl[nt], 0, 0, 0);
      }
    }

    // ---- phase E: K-partial exchange + gates (ONE barrier per step)
    if (lane < 16) {
#pragma unroll
      for (int nt = 0; nt < 4; ++nt)
#pragma unroll
        for (int r = 0; r < 4; ++r)
          gLDS[t & 1][gw][nt][r][lane] = acc[nt][r] + accl[nt][r];
    }
    __syncthreads();

    float v4[4];
#pragma unroll
    for (int gg2 = 0; gg2 < 4; ++gg2) {
      float sum = bias4[gg2];
#pragma unroll
      for (int w = 0; w < 4; ++w) sum += gLDS[t & 1][w][gg2][gb][gu];
      v4[gg2] = sum;
    }
    float ig = fast_sigmoid(v4[0]);
    float fg = fast_sigmoid(v4[1]);
    float og = fast_sigmoid(v4[2]);
    float gg3 = fast_tanh(v4[3]);
    c = fg * c + ig * gg3;
    float h = og * fast_tanh(c);

    // ---- phase F: publish (wave 0): 4 replicas -> vmcnt(0) -> flag bump
    if (gw == 0 && t + 1 < T_STEPS) {
      const unsigned ntag = (unsigned)(((t + 1) >> 3) & 3);
      float ha = __shfl(h, shfl_src);
      float hbv = __shfl(h, shfl_src + 1);
      unsigned short hiA = (unsigned short)((f2bf(ha) & 0xFFFCu) | ntag);
      unsigned short loA = (unsigned short)((f2bf(ha - bf2f(hiA)) & 0xFFFCu) | ntag);
      unsigned short hiB = (unsigned short)((f2bf(hbv) & 0xFFFCu) | ntag);
      unsigned short loB = (unsigned short)((f2bf(hbv - bf2f(hiB)) & 0xFFFCu) | ntag);
      unsigned whi = (unsigned)hiA | ((unsigned)hiB << 16);
      unsigned wlo = (unsigned)loA | ((unsigned)loB << 16);
      if (lane < 32) {
        const int b = lane >> 3, u2 = (lane & 7) * 2;
        unsigned short* wr = hb + ((t + 1) & 7) * 16384;
        if (use_direct) {
#pragma unroll
          for (int rep = 0; rep < 4; ++rep) {
            *(unsigned*)&wr[rep * 4096 + b * 512 + s * 16 + u2] = whi;
            *(unsigned*)&wr[rep * 4096 + 2048 + b * 512 + s * 16 + u2] = wlo;
          }
        } else {
#pragma unroll
          for (int rep = 0; rep < 4; ++rep) {
            __hip_atomic_store((unsigned*)&wr[rep * 4096 + b * 512 + s * 16 + u2], whi,
                               __ATOMIC_RELAXED, __HIP_MEMORY_SCOPE_AGENT);
            __hip_atomic_store((unsigned*)&wr[rep * 4096 + 2048 + b * 512 + s * 16 + u2], wlo,
                               __ATOMIC_RELAXED, __HIP_MEMORY_SCOPE_AGENT);
          }
        }
      }
      asm volatile("s_waitcnt vmcnt(0)" ::: "memory");           // data visible first
      if (lane == 0) {
        int one = 1;
        asm volatile("global_atomic_add %0, %1, off" :: "v"(myflag), "v"(one) : "memory");
      }
    }

    // ---- phase G: out store (wave 1 only) + x prefetch
    if (gw == 1) outbase[(size_t)t * 512] = h;
    {
      const int tn = (t + 1 < T_STEPS) ? (t + 1) : t;
      const unsigned short* xt1 = xb + (size_t)tn * 16384;
#pragma unroll
      for (int kt = 0; kt < 4; ++kt) {
        const int k0 = (gw << 7) + (kt << 5) + kgrp;
        xf[kt] = *(const short8*)&xt1[xrow + k0];
      }
    }
  }
}

extern "C" void kernel_launch(void* const* d_in, const int* in_sizes, int n_in,
                              void* d_out, int out_size, void* d_ws, size_t ws_size,
                              hipStream_t stream) {
  const float* x = (const float*)d_in[0];     // (32, 2048, 512) f32
  const float* h0 = (const float*)d_in[1];    // (32, 512) f32
  const float* Wx = (const float*)d_in[2];    // (512, 2048) f32
  const float* Wh = (const float*)d_in[3];    // (512, 2048) f32
  const float* bias = (const float*)d_in[4];  // (2048,) f32
  float* out = (float*)d_out;

  char* ws = (char*)d_ws;
  unsigned short* wxp = (unsigned short*)(ws);                            // 2 MB
  unsigned short* whp = (unsigned short*)(ws + (2u << 20));               // 2 MB
  unsigned short* hbuf = (unsigned short*)(ws + (4u << 20));              // 2 MB (8 x 256KB)
  int* ctl = (int*)(ws + (6u << 20) + (512u << 10));                      // 36 B
  int* flags = (int*)(ws + (7u << 20));                                   // 32 KB
  unsigned short* xb = (unsigned short*)(ws + (8u << 20));                // 64 MB

  hipLaunchKernelGGL(prep_kernel, dim3(8289), dim3(256), 0, stream,
                     Wx, Wh, h0, wxp, whp, hbuf, ctl, flags);
  hipLaunchKernelGGL(xprep_kernel, dim3(16384), dim3(256), 0, stream, x, xb);
  hipLaunchKernelGGL(scan_kernel, dim3(256), dim3(256), 0, stream,
                     xb, bias, wxp, whp, hbuf, out, ctl, flags);
}